// Round 14
// baseline (146.080 us; speedup 1.0000x reference)
//
#include <hip/hip_runtime.h>
#include <cstdint>
#include <cstddef>

constexpr int O_C   = 16;     // objects per image
constexpr int P_MAX = 8732;   // priors
constexpr int CH    = 4;      // match chunks per batch
constexpr int CHP   = 2183;   // priors per chunk (4*2183 = 8732)

__device__ __forceinline__ float waveSumF(float v) {
    #pragma unroll
    for (int off = 32; off; off >>= 1) v += __shfl_xor(v, off);
    return v;
}
__device__ __forceinline__ int waveSumI(int v) {
    #pragma unroll
    for (int off = 32; off; off >>= 1) v += __shfl_xor(v, off);
    return v;
}

// ---------------------------------------------------------------------------
// K1: blocks [0, nlse)        : PURE streaming LSE (thread-per-row, aligned
//                               dwordx4 window, no LDS, no barriers).
//     blocks [nlse, nlse+256) : per-batch-chunk match -> okey_part only.
//     block 0 thread 0        : resets K2's completion counter.
// The two halves are data-independent; match hides under the stream.
// ---------------------------------------------------------------------------
__global__ __launch_bounds__(256) void k1_lse_match(
    const float* __restrict__ confs,          // [rows,81]
    const float* __restrict__ target_boxes,   // [B,O,4] xyxy
    const float* __restrict__ priors,         // [P,4] cxcywh
    unsigned long long* __restrict__ okey_part, // [nmatch*O]
    float* __restrict__ lse_out,              // [rows]
    int* __restrict__ counter,                // K2 completion counter
    int P, int nlse)
{
    const int tid  = threadIdx.x;
    const int lane = tid & 63;
    const int wid  = tid >> 6;

    if (blockIdx.x == 0 && tid == 0) *counter = 0;   // K1 completes before K2

    if (blockIdx.x < (unsigned)nlse) {
        // ---- pure LSE: floats [81r, 81r+81) in aligned float4 window ----
        const int row = blockIdx.x * 256 + tid;
        const int phase = row & 3;                 // (81*row) % 4 == row % 4
        const float4* vp = reinterpret_cast<const float4*>(confs)
                         + (((size_t)row * 81) >> 2);

        float mA = -3.0e38f, sA = 0.0f;
        float mB = -3.0e38f, sB = 0.0f;
        #pragma unroll
        for (int j = 0; j < 21; ++j) {
            float4 v = vp[j];
            const int eb = 4 * j - phase;
            float x0 = ((unsigned)(eb + 0) < 81u) ? v.x : -3.0e38f;
            float x1 = ((unsigned)(eb + 1) < 81u) ? v.y : -3.0e38f;
            float x2 = ((unsigned)(eb + 2) < 81u) ? v.z : -3.0e38f;
            float x3 = ((unsigned)(eb + 3) < 81u) ? v.w : -3.0e38f;
            float m4 = fmaxf(fmaxf(x0, x1), fmaxf(x2, x3));
            if (j & 1) {
                float mn = fmaxf(mB, m4);
                sB = sB * __expf(mB - mn)
                   + __expf(x0 - mn) + __expf(x1 - mn)
                   + __expf(x2 - mn) + __expf(x3 - mn);
                mB = mn;
            } else {
                float mn = fmaxf(mA, m4);
                sA = sA * __expf(mA - mn)
                   + __expf(x0 - mn) + __expf(x1 - mn)
                   + __expf(x2 - mn) + __expf(x3 - mn);
                mA = mn;
            }
        }
        float m = fmaxf(mA, mB);
        float s = sA * __expf(mA - m) + sB * __expf(mB - m);
        lse_out[row] = m + __logf(s);
        return;
    }

    // ---- match chunk: per-object best-prior candidate keys ----
    __shared__ float bx0[O_C], by0[O_C], bx1[O_C], by1[O_C], barea[O_C];
    __shared__ unsigned long long s_wb[O_C * 4];

    const int chunk = blockIdx.x - nlse;
    const int b = chunk / CH;
    const int c = chunk % CH;

    if (tid < O_C) {
        const float* tb = target_boxes + ((size_t)b * O_C + tid) * 4;
        float x0 = tb[0], y0 = tb[1], x1 = tb[2], y1 = tb[3];
        bx0[tid] = x0; by0[tid] = y0; bx1[tid] = x1; by1[tid] = y1;
        barea[tid] = (x1 - x0) * (y1 - y0);
    }
    __syncthreads();

    float bi[O_C]; int bp[O_C];
    #pragma unroll
    for (int o = 0; o < O_C; ++o) { bi[o] = -1.0f; bp[o] = 0; }

    const int p0 = c * CHP, p1 = min(p0 + CHP, P);
    for (int p = p0 + tid; p < p1; p += 256) {
        float4 pr = reinterpret_cast<const float4*>(priors)[p];
        float px0 = pr.x - pr.z * 0.5f, py0 = pr.y - pr.w * 0.5f;
        float px1 = pr.x + pr.z * 0.5f, py1 = pr.y + pr.w * 0.5f;
        float parea = (px1 - px0) * (py1 - py0);
        #pragma unroll
        for (int o = 0; o < O_C; ++o) {
            float ix0 = fmaxf(px0, bx0[o]), iy0 = fmaxf(py0, by0[o]);
            float ix1 = fminf(px1, bx1[o]), iy1 = fminf(py1, by1[o]);
            float iw = fmaxf(ix1 - ix0, 0.0f), ih = fmaxf(iy1 - iy0, 0.0f);
            float inter = iw * ih;
            float iou = inter / (barea[o] + parea - inter);
            if (iou > bi[o]) { bi[o] = iou; bp[o] = p; }  // strict > -> smallest p
        }
    }

    #pragma unroll
    for (int o = 0; o < O_C; ++o) {
        unsigned long long k = (bi[o] >= 0.0f)
            ? (((unsigned long long)__float_as_uint(bi[o]) << 32) |
               (unsigned long long)(0xFFFFFFFFu - (unsigned)bp[o]))
            : 0ull;
        #pragma unroll
        for (int off = 32; off; off >>= 1) {
            unsigned long long k2 = __shfl_xor(k, off);
            if (k2 > k) k = k2;
        }
        if (lane == 0) s_wb[o * 4 + wid] = k;
    }
    __syncthreads();
    if (tid < O_C) {
        unsigned long long k = s_wb[tid * 4];
        #pragma unroll
        for (int w = 1; w < 4; ++w) if (s_wb[tid * 4 + w] > k) k = s_wb[tid * 4 + w];
        okey_part[(size_t)chunk * O_C + tid] = k;
    }
}

// ---------------------------------------------------------------------------
// K2: per-batch block. Recomputes per-prior IoU argmax (bit-identical ops),
// forced-match override, ce = lse - confs[row*81+l], pos/neg/loc sums,
// exact top-K negative sum via radix select. LAST block (atomic counter)
// computes the final scalar loss — no separate finalize node.
// ---------------------------------------------------------------------------
__global__ __launch_bounds__(1024) void k2_hard_finalize(
    const float* __restrict__ confs,          // [rows,81]
    const float* __restrict__ lse,            // [rows]
    const unsigned long long* __restrict__ okey_part, // [B*CH*O]
    const float* __restrict__ target_boxes,   // [B,O,4]
    const int*   __restrict__ target_labels,  // [B,O]
    const float* __restrict__ priors,         // [P,4]
    const float* __restrict__ predict_locs,   // [B,P,4]
    int*   __restrict__ n_pos,                // [B]
    float* __restrict__ ce_pos,               // [B]
    float* __restrict__ ce_hard,              // [B]
    float* __restrict__ loc_b,                // [B]
    int*   __restrict__ counter,              // completion counter (K1 reset)
    float* __restrict__ out,
    int P, int B)
{
    const int b    = blockIdx.x;
    const int tid  = threadIdx.x;
    const int lane = tid & 63;
    const int wid  = tid >> 6;

    __shared__ float s_v[P_MAX];
    __shared__ unsigned int hist[16][256];
    __shared__ float4 tbox[O_C];
    __shared__ float  tarea[O_C];
    __shared__ int    tlab[O_C], topr[O_C];
    __shared__ unsigned int s_sel;
    __shared__ int s_kr, s_last;
    __shared__ float s_f[16], s_f2[16], s_f3[16];
    __shared__ int s_i[16];

    if (tid < O_C) {
        const float* tb = target_boxes + ((size_t)b * O_C + tid) * 4;
        float x0 = tb[0], y0 = tb[1], x1 = tb[2], y1 = tb[3];
        tbox[tid]  = make_float4(x0, y0, x1, y1);
        tarea[tid] = (x1 - x0) * (y1 - y0);
        tlab[tid]  = target_labels[(size_t)b * O_C + tid];
        unsigned long long kk = 0ull;
        #pragma unroll
        for (int cc = 0; cc < CH; ++cc) {
            unsigned long long k2 = okey_part[((size_t)b * CH + cc) * O_C + tid];
            if (k2 > kk) kk = k2;
        }
        topr[tid] = (int)(0xFFFFFFFFu - (unsigned)(kk & 0xFFFFFFFFull));
    }
    __syncthreads();

    const size_t base = (size_t)b * P;
    float possum = 0.0f, negsum = 0.0f, locsum = 0.0f;
    int cnt = 0;
    for (int p = tid; p < P; p += 1024) {
        // per-prior IoU argmax: identical ops/order to reference matching
        float4 pr = reinterpret_cast<const float4*>(priors)[p];
        float px0 = pr.x - pr.z * 0.5f, py0 = pr.y - pr.w * 0.5f;
        float px1 = pr.x + pr.z * 0.5f, py1 = pr.y + pr.w * 0.5f;
        float parea = (px1 - px0) * (py1 - py0);
        float bv = -1.0f; int bo = 0;
        #pragma unroll
        for (int o = 0; o < O_C; ++o) {
            float4 tb = tbox[o];
            float ix0 = fmaxf(px0, tb.x), iy0 = fmaxf(py0, tb.y);
            float ix1 = fminf(px1, tb.z), iy1 = fminf(py1, tb.w);
            float iw = fmaxf(ix1 - ix0, 0.0f), ih = fmaxf(iy1 - iy0, 0.0f);
            float inter = iw * ih;
            float iou = inter / (tarea[o] + parea - inter);
            if (iou > bv) { bv = iou; bo = o; }   // first-max (argmax over o)
        }
        float ovv = bv;
        int   obj = bo;
        #pragma unroll
        for (int o = 0; o < O_C; ++o)             // ascending -> last write wins
            if (topr[o] == p) { obj = o; ovv = 1.0f; }
        const int l = (ovv < 0.5f) ? 0 : tlab[obj];

        float xl  = confs[(base + p) * 81 + l];
        float cev = lse[base + p] - xl;
        if (l != 0) {
            possum += cev; ++cnt;
            s_v[p] = 0.0f;
            float4 tb = tbox[obj];
            float cx = (tb.x + tb.z) * 0.5f, cy = (tb.y + tb.w) * 0.5f;
            float w  = tb.z - tb.x,          h  = tb.w - tb.y;
            float g0 = (cx - pr.x) / (pr.z * 0.1f);
            float g1 = (cy - pr.y) / (pr.w * 0.1f);
            float g2 = logf(w / pr.z) / 0.2f;
            float g3 = logf(h / pr.w) / 0.2f;
            float4 pl = reinterpret_cast<const float4*>(predict_locs)[base + p];
            locsum += fabsf(pl.x - g0) + fabsf(pl.y - g1) +
                      fabsf(pl.z - g2) + fabsf(pl.w - g3);
        } else {
            negsum += cev;
            s_v[p] = cev;
        }
    }
    possum = waveSumF(possum);
    negsum = waveSumF(negsum);
    locsum = waveSumF(locsum);
    cnt    = waveSumI(cnt);
    if (lane == 0) { s_f[wid] = possum; s_f2[wid] = negsum; s_f3[wid] = locsum; s_i[wid] = cnt; }
    __syncthreads();
    float negsum_t = 0.0f, possum_t = 0.0f, locsum_t = 0.0f; int np = 0;
    #pragma unroll
    for (int w = 0; w < 16; ++w) {
        negsum_t += s_f2[w]; possum_t += s_f[w]; locsum_t += s_f3[w]; np += s_i[w];
    }
    if (tid == 0) { ce_pos[b] = possum_t; n_pos[b] = np; loc_b[b] = locsum_t; }

    const int K = 3 * np;
    if (K <= 0) {
        if (tid == 0) ce_hard[b] = 0.0f;
    } else if (K >= P) {
        if (tid == 0) ce_hard[b] = negsum_t;
    } else {
        unsigned int prefix = 0; int kr = K;
        for (int shift = 24; shift >= 0; shift -= 8) {
            for (int i = tid; i < 16 * 256; i += 1024) (&hist[0][0])[i] = 0;
            __syncthreads();
            unsigned int maskHi = (shift == 24) ? 0u : (0xFFFFFFFFu << (shift + 8));
            for (int p = tid; p < P; p += 1024) {
                unsigned int u = __float_as_uint(s_v[p]);
                if ((u & maskHi) == prefix) atomicAdd(&hist[wid][(u >> shift) & 255], 1u);
            }
            __syncthreads();
            if (wid == 0) {
                unsigned h0 = 0, h1 = 0, h2 = 0, h3 = 0;
                #pragma unroll 4
                for (int w = 0; w < 16; ++w) {
                    h0 += hist[w][lane * 4 + 0];
                    h1 += hist[w][lane * 4 + 1];
                    h2 += hist[w][lane * 4 + 2];
                    h3 += hist[w][lane * 4 + 3];
                }
                unsigned own = h0 + h1 + h2 + h3;
                unsigned t = own;                    // inclusive suffix over lanes
                #pragma unroll
                for (int off = 1; off < 64; off <<= 1) {
                    unsigned u = __shfl_down(t, off);
                    if (lane + off >= 64) u = 0;
                    t += u;
                }
                unsigned Tnext = t - own;            // strictly-higher lanes
                unsigned cum3 = Tnext;
                unsigned cum2 = cum3 + h3;
                unsigned cum1 = cum2 + h2;
                unsigned cum0 = cum1 + h1;
                unsigned kru = (unsigned)kr;
                int selj = -1; unsigned cg = 0;
                if      (cum3 < kru && kru <= cum3 + h3) { selj = 3; cg = cum3; }
                else if (cum2 < kru && kru <= cum2 + h2) { selj = 2; cg = cum2; }
                else if (cum1 < kru && kru <= cum1 + h1) { selj = 1; cg = cum1; }
                else if (cum0 < kru && kru <= cum0 + h0) { selj = 0; cg = cum0; }
                if (selj >= 0) {
                    s_sel = prefix | ((unsigned)(lane * 4 + selj) << shift);
                    s_kr  = kr - (int)cg;
                }
            }
            __syncthreads();
            prefix = s_sel; kr = s_kr;
            __syncthreads();
        }

        float sumgt = 0.0f;
        for (int p = tid; p < P; p += 1024) {
            unsigned int u = __float_as_uint(s_v[p]);
            if (u > prefix) sumgt += s_v[p];
        }
        sumgt = waveSumF(sumgt);
        if (lane == 0) s_f[wid] = sumgt;
        __syncthreads();
        if (tid == 0) {
            float sg = 0.0f;
            #pragma unroll
            for (int w = 0; w < 16; ++w) sg += s_f[w];
            ce_hard[b] = sg + (float)kr * __uint_as_float(prefix);
        }
    }

    // ---- last-block finalize (deterministic: all inputs written first) ----
    __threadfence();
    __syncthreads();
    if (tid == 0) s_last = (atomicAdd(counter, 1) == B - 1) ? 1 : 0;
    __syncthreads();
    if (s_last) {
        __threadfence();   // acquire: see all blocks' writes
        if (tid < 64) {
            int npT = 0; float cp = 0.0f, chd = 0.0f, la = 0.0f;
            for (int bb = tid; bb < B; bb += 64) {
                npT += n_pos[bb]; cp += ce_pos[bb];
                chd += ce_hard[bb]; la += loc_b[bb];
            }
            #pragma unroll
            for (int off = 32; off; off >>= 1) {
                npT += __shfl_xor(npT, off);
                cp  += __shfl_xor(cp, off);
                chd += __shfl_xor(chd, off);
                la  += __shfl_xor(la, off);
            }
            if (tid == 0) {
                float npt = (float)npT;
                out[0] = (chd + cp) / npt + la / (npt * 4.0f);
            }
        }
    }
}

extern "C" void kernel_launch(void* const* d_in, const int* in_sizes, int n_in,
                              void* d_out, int out_size, void* d_ws, size_t ws_size,
                              hipStream_t stream) {
    const float* predict_locs  = (const float*)d_in[0];
    const float* predict_confs = (const float*)d_in[1];
    const float* target_boxes  = (const float*)d_in[2];
    const int*   target_labels = (const int*)d_in[3];
    const float* priors        = (const float*)d_in[4];

    const int P = in_sizes[4] / 4;             // 8732
    const int B = in_sizes[0] / (P * 4);       // 64
    const int rows = B * P;                    // 558848
    const int nmatch = B * CH;                 // 256
    const int nlse = rows / 256;               // 2183 (rows % 256 == 0)

    char* ws = (char*)d_ws;
    unsigned long long* okey_part = (unsigned long long*)ws;
    ws += (size_t)nmatch * O_C * sizeof(unsigned long long);
    float* lse     = (float*)ws; ws += (size_t)rows * sizeof(float);
    int*   n_pos   = (int*)ws;   ws += (size_t)B * sizeof(int);
    float* ce_pos  = (float*)ws; ws += (size_t)B * sizeof(float);
    float* ce_hard = (float*)ws; ws += (size_t)B * sizeof(float);
    float* loc_b   = (float*)ws; ws += (size_t)B * sizeof(float);
    int*   counter = (int*)ws;   ws += sizeof(int);

    k1_lse_match<<<nlse + nmatch, 256, 0, stream>>>(
        predict_confs, target_boxes, priors, okey_part, lse, counter, P, nlse);
    k2_hard_finalize<<<B, 1024, 0, stream>>>(
        predict_confs, lse, okey_part, target_boxes, target_labels,
        priors, predict_locs, n_pos, ce_pos, ce_hard, loc_b, counter,
        (float*)d_out, P, B);
}

// Round 15
// 100.192 us; speedup vs baseline: 1.4580x; 1.4580x over previous
//
#include <hip/hip_runtime.h>
#include <cstdint>
#include <cstddef>

constexpr int O_C   = 16;     // objects per image
constexpr int P_MAX = 8732;   // priors
constexpr int CH    = 4;      // match chunks per batch
constexpr int CHP   = 2183;   // priors per chunk (4*2183 = 8732)

__device__ __forceinline__ float waveSumF(float v) {
    #pragma unroll
    for (int off = 32; off; off >>= 1) v += __shfl_xor(v, off);
    return v;
}
__device__ __forceinline__ int waveSumI(int v) {
    #pragma unroll
    for (int off = 32; off; off >>= 1) v += __shfl_xor(v, off);
    return v;
}

// ---------------------------------------------------------------------------
// K0: okey-only match. grid = B*CH blocks, 256 thr. Per-(chunk,object)
// best-prior candidate keys; no ov/obj materialization. Resets K2 counter.
// ---------------------------------------------------------------------------
__global__ __launch_bounds__(256) void match_okey(
    const float* __restrict__ target_boxes,   // [B,O,4] xyxy
    const float* __restrict__ priors,         // [P,4] cxcywh
    unsigned long long* __restrict__ okey_part, // [B*CH*O]
    int* __restrict__ counter,
    int P)
{
    const int b    = blockIdx.x / CH;
    const int c    = blockIdx.x % CH;
    const int tid  = threadIdx.x;
    const int lane = tid & 63;
    const int wid  = tid >> 6;

    if (blockIdx.x == 0 && tid == 0) *counter = 0;

    __shared__ float bx0[O_C], by0[O_C], bx1[O_C], by1[O_C], barea[O_C];
    __shared__ unsigned long long s_wb[O_C * 4];

    if (tid < O_C) {
        const float* tb = target_boxes + ((size_t)b * O_C + tid) * 4;
        float x0 = tb[0], y0 = tb[1], x1 = tb[2], y1 = tb[3];
        bx0[tid] = x0; by0[tid] = y0; bx1[tid] = x1; by1[tid] = y1;
        barea[tid] = (x1 - x0) * (y1 - y0);
    }
    __syncthreads();

    float bi[O_C]; int bp[O_C];
    #pragma unroll
    for (int o = 0; o < O_C; ++o) { bi[o] = -1.0f; bp[o] = 0; }

    const int p0 = c * CHP, p1 = min(p0 + CHP, P);
    for (int p = p0 + tid; p < p1; p += 256) {
        float4 pr = reinterpret_cast<const float4*>(priors)[p];
        float px0 = pr.x - pr.z * 0.5f, py0 = pr.y - pr.w * 0.5f;
        float px1 = pr.x + pr.z * 0.5f, py1 = pr.y + pr.w * 0.5f;
        float parea = (px1 - px0) * (py1 - py0);
        #pragma unroll
        for (int o = 0; o < O_C; ++o) {
            float ix0 = fmaxf(px0, bx0[o]), iy0 = fmaxf(py0, by0[o]);
            float ix1 = fminf(px1, bx1[o]), iy1 = fminf(py1, by1[o]);
            float iw = fmaxf(ix1 - ix0, 0.0f), ih = fmaxf(iy1 - iy0, 0.0f);
            float inter = iw * ih;
            float iou = inter / (barea[o] + parea - inter);
            if (iou > bi[o]) { bi[o] = iou; bp[o] = p; }  // strict > -> smallest p
        }
    }

    #pragma unroll
    for (int o = 0; o < O_C; ++o) {
        unsigned long long k = (bi[o] >= 0.0f)
            ? (((unsigned long long)__float_as_uint(bi[o]) << 32) |
               (unsigned long long)(0xFFFFFFFFu - (unsigned)bp[o]))
            : 0ull;
        #pragma unroll
        for (int off = 32; off; off >>= 1) {
            unsigned long long k2 = __shfl_xor(k, off);
            if (k2 > k) k = k2;
        }
        if (lane == 0) s_wb[o * 4 + wid] = k;
    }
    __syncthreads();
    if (tid < O_C) {
        unsigned long long k = s_wb[tid * 4];
        #pragma unroll
        for (int w = 1; w < 4; ++w) if (s_wb[tid * 4 + w] > k) k = s_wb[tid * 4 + w];
        okey_part[(size_t)blockIdx.x * O_C + tid] = k;   // [b][c][o]
    }
}

// ---------------------------------------------------------------------------
// K1: thread-per-row fused CE (champion structure). Aligned dwordx4 window
// LSE + INLINE per-prior IoU argmax recompute (bit-identical op order) +
// forced-match override + loc partial. SIGNED ce output. No ov/obj arrays.
// ---------------------------------------------------------------------------
__global__ __launch_bounds__(256) void ce_stream(
    const float* __restrict__ confs,            // [rows,81]
    const unsigned long long* __restrict__ okey_part, // [B*CH*O]
    const float* __restrict__ target_boxes,     // [B,O,4]
    const int*   __restrict__ target_labels,    // [B,O]
    const float* __restrict__ priors,           // [P,4]
    const float* __restrict__ predict_locs,     // [rows,4]
    float* __restrict__ ce_out,                 // [rows] signed
    float* __restrict__ loc_part,               // [nblocks]
    int P, int rows)
{
    const int tid  = threadIdx.x;
    const int lane = tid & 63;
    const int wid  = tid >> 6;
    const int row0 = blockIdx.x * 256;
    const int row  = row0 + tid;

    __shared__ float4 tbox[2][O_C];
    __shared__ float  tarea[2][O_C];
    __shared__ int    tlab[2][O_C], topr[2][O_C];
    __shared__ float  s_facc[4];

    const int b0     = row0 / P;
    const int rsplit = min(row0 + 256, (b0 + 1) * P);
    const int b1     = (rsplit < row0 + 256) ? b0 + 1 : b0;

    if (tid < 2 * O_C) {
        const int seg = tid >> 4, o = tid & 15;
        const int bb  = seg ? b1 : b0;
        const float* tb = target_boxes + ((size_t)bb * O_C + o) * 4;
        float x0 = tb[0], y0 = tb[1], x1 = tb[2], y1 = tb[3];
        tbox[seg][o]  = make_float4(x0, y0, x1, y1);
        tarea[seg][o] = (x1 - x0) * (y1 - y0);
        tlab[seg][o]  = target_labels[(size_t)bb * O_C + o];
        unsigned long long kk = 0ull;
        #pragma unroll
        for (int cc = 0; cc < CH; ++cc) {
            unsigned long long k2 = okey_part[((size_t)bb * CH + cc) * O_C + o];
            if (k2 > kk) kk = k2;
        }
        topr[seg][o] = (int)(0xFFFFFFFFu - (unsigned)(kk & 0xFFFFFFFFull));
    }
    __syncthreads();

    // ---- streaming LSE over aligned dwordx4 window ----
    const int phase = row & 3;                 // (81*row) % 4 == row % 4
    const float4* vp = reinterpret_cast<const float4*>(confs)
                     + (((size_t)row * 81) >> 2);

    float mA = -3.0e38f, sA = 0.0f;
    float mB = -3.0e38f, sB = 0.0f;
    #pragma unroll
    for (int j = 0; j < 21; ++j) {
        float4 v = vp[j];
        const int eb = 4 * j - phase;
        float x0 = ((unsigned)(eb + 0) < 81u) ? v.x : -3.0e38f;
        float x1 = ((unsigned)(eb + 1) < 81u) ? v.y : -3.0e38f;
        float x2 = ((unsigned)(eb + 2) < 81u) ? v.z : -3.0e38f;
        float x3 = ((unsigned)(eb + 3) < 81u) ? v.w : -3.0e38f;
        float m4 = fmaxf(fmaxf(x0, x1), fmaxf(x2, x3));
        if (j & 1) {
            float mn = fmaxf(mB, m4);
            sB = sB * __expf(mB - mn)
               + __expf(x0 - mn) + __expf(x1 - mn)
               + __expf(x2 - mn) + __expf(x3 - mn);
            mB = mn;
        } else {
            float mn = fmaxf(mA, m4);
            sA = sA * __expf(mA - mn)
               + __expf(x0 - mn) + __expf(x1 - mn)
               + __expf(x2 - mn) + __expf(x3 - mn);
            mA = mn;
        }
    }
    float m = fmaxf(mA, mB);
    float s = sA * __expf(mA - m) + sB * __expf(mB - m);

    // ---- inline per-prior IoU argmax (identical ops/order as reference) ----
    const int seg = (row >= rsplit) ? 1 : 0;
    const int bb  = seg ? b1 : b0;
    const int p   = row - bb * P;

    float4 pr = reinterpret_cast<const float4*>(priors)[p];
    float px0 = pr.x - pr.z * 0.5f, py0 = pr.y - pr.w * 0.5f;
    float px1 = pr.x + pr.z * 0.5f, py1 = pr.y + pr.w * 0.5f;
    float parea = (px1 - px0) * (py1 - py0);
    float ovv = -1.0f; int obj = 0;
    #pragma unroll
    for (int o = 0; o < O_C; ++o) {
        float4 tb = tbox[seg][o];
        float ix0 = fmaxf(px0, tb.x), iy0 = fmaxf(py0, tb.y);
        float ix1 = fminf(px1, tb.z), iy1 = fminf(py1, tb.w);
        float iw = fmaxf(ix1 - ix0, 0.0f), ih = fmaxf(iy1 - iy0, 0.0f);
        float inter = iw * ih;
        float iou = inter / (tarea[seg][o] + parea - inter);
        if (iou > ovv) { ovv = iou; obj = o; }   // first-max (argmax over o)
    }
    #pragma unroll
    for (int o = 0; o < O_C; ++o)                // ascending -> last write wins
        if (topr[seg][o] == p) { obj = o; ovv = 1.0f; }
    const int l = (ovv < 0.5f) ? 0 : tlab[seg][obj];

    float xl  = confs[(size_t)row * 81 + l];     // L1-hot after the stream
    float cev = m + __logf(s) - xl;
    ce_out[row] = l ? -cev : cev;                // sign bit carries pos/neg

    float locacc = 0.0f;
    if (l) {
        float4 tb = tbox[seg][obj];
        float cx = (tb.x + tb.z) * 0.5f, cy = (tb.y + tb.w) * 0.5f;
        float w  = tb.z - tb.x,          h  = tb.w - tb.y;
        float g0 = (cx - pr.x) / (pr.z * 0.1f);
        float g1 = (cy - pr.y) / (pr.w * 0.1f);
        float g2 = logf(w / pr.z) / 0.2f;
        float g3 = logf(h / pr.w) / 0.2f;
        float4 pl = reinterpret_cast<const float4*>(predict_locs)[row];
        locacc = fabsf(pl.x - g0) + fabsf(pl.y - g1) +
                 fabsf(pl.z - g2) + fabsf(pl.w - g3);
    }
    float a = waveSumF(locacc);
    if (lane == 0) s_facc[wid] = a;
    __syncthreads();
    if (tid == 0)
        loc_part[blockIdx.x] = s_facc[0] + s_facc[1] + s_facc[2] + s_facc[3];
}

// ---------------------------------------------------------------------------
// K2: per-batch hard-negative mining from signed ce + LAST-BLOCK finalize.
// ---------------------------------------------------------------------------
__global__ __launch_bounds__(1024) void hard_finalize(
    const float* __restrict__ ce,       // [B,P] signed
    const float* __restrict__ loc_part, // [nblk]
    int*   __restrict__ n_pos,          // [B]
    float* __restrict__ ce_pos,         // [B]
    float* __restrict__ ce_hard,        // [B]
    int*   __restrict__ counter,
    float* __restrict__ out,
    int P, int B, int nblk)
{
    const int b    = blockIdx.x;
    const int tid  = threadIdx.x;
    const int lane = tid & 63;
    const int wid  = tid >> 6;

    __shared__ float s_v[P_MAX];
    __shared__ unsigned int hist[16][256];
    __shared__ unsigned int s_sel;
    __shared__ int s_kr, s_last;
    __shared__ float s_f[16], s_f2[16];
    __shared__ int s_i[16];

    const size_t base = (size_t)b * P;
    float possum = 0.0f, negsum = 0.0f;
    int cnt = 0;
    for (int p = tid; p < P; p += 1024) {
        float c = ce[base + p];
        unsigned u = __float_as_uint(c);
        float sv;
        if (u >> 31) { possum += -c; ++cnt; sv = 0.0f; }
        else         { negsum += c;         sv = c;    }
        s_v[p] = sv;
    }
    possum = waveSumF(possum);
    negsum = waveSumF(negsum);
    cnt    = waveSumI(cnt);
    if (lane == 0) { s_f[wid] = possum; s_f2[wid] = negsum; s_i[wid] = cnt; }
    __syncthreads();
    float negsum_t = 0.0f, possum_t = 0.0f; int np = 0;
    #pragma unroll
    for (int w = 0; w < 16; ++w) { negsum_t += s_f2[w]; possum_t += s_f[w]; np += s_i[w]; }
    if (tid == 0) { ce_pos[b] = possum_t; n_pos[b] = np; }

    const int K = 3 * np;
    if (K <= 0) {
        if (tid == 0) ce_hard[b] = 0.0f;
    } else if (K >= P) {
        if (tid == 0) ce_hard[b] = negsum_t;
    } else {
        unsigned int prefix = 0; int kr = K;
        for (int shift = 24; shift >= 0; shift -= 8) {
            for (int i = tid; i < 16 * 256; i += 1024) (&hist[0][0])[i] = 0;
            __syncthreads();
            unsigned int maskHi = (shift == 24) ? 0u : (0xFFFFFFFFu << (shift + 8));
            for (int p = tid; p < P; p += 1024) {
                unsigned int u = __float_as_uint(s_v[p]);
                if ((u & maskHi) == prefix) atomicAdd(&hist[wid][(u >> shift) & 255], 1u);
            }
            __syncthreads();
            if (wid == 0) {
                unsigned h0 = 0, h1 = 0, h2 = 0, h3 = 0;
                #pragma unroll 4
                for (int w = 0; w < 16; ++w) {
                    h0 += hist[w][lane * 4 + 0];
                    h1 += hist[w][lane * 4 + 1];
                    h2 += hist[w][lane * 4 + 2];
                    h3 += hist[w][lane * 4 + 3];
                }
                unsigned own = h0 + h1 + h2 + h3;
                unsigned t = own;                    // inclusive suffix over lanes
                #pragma unroll
                for (int off = 1; off < 64; off <<= 1) {
                    unsigned u = __shfl_down(t, off);
                    if (lane + off >= 64) u = 0;
                    t += u;
                }
                unsigned Tnext = t - own;            // strictly-higher lanes
                unsigned cum3 = Tnext;
                unsigned cum2 = cum3 + h3;
                unsigned cum1 = cum2 + h2;
                unsigned cum0 = cum1 + h1;
                unsigned kru = (unsigned)kr;
                int selj = -1; unsigned cg = 0;
                if      (cum3 < kru && kru <= cum3 + h3) { selj = 3; cg = cum3; }
                else if (cum2 < kru && kru <= cum2 + h2) { selj = 2; cg = cum2; }
                else if (cum1 < kru && kru <= cum1 + h1) { selj = 1; cg = cum1; }
                else if (cum0 < kru && kru <= cum0 + h0) { selj = 0; cg = cum0; }
                if (selj >= 0) {
                    s_sel = prefix | ((unsigned)(lane * 4 + selj) << shift);
                    s_kr  = kr - (int)cg;
                }
            }
            __syncthreads();
            prefix = s_sel; kr = s_kr;
            __syncthreads();
        }

        float sumgt = 0.0f;
        for (int p = tid; p < P; p += 1024) {
            unsigned int u = __float_as_uint(s_v[p]);
            if (u > prefix) sumgt += s_v[p];
        }
        sumgt = waveSumF(sumgt);
        if (lane == 0) s_f[wid] = sumgt;
        __syncthreads();
        if (tid == 0) {
            float sg = 0.0f;
            #pragma unroll
            for (int w = 0; w < 16; ++w) sg += s_f[w];
            ce_hard[b] = sg + (float)kr * __uint_as_float(prefix);
        }
    }

    // ---- last-block finalize ----
    __threadfence();
    __syncthreads();
    if (tid == 0) s_last = (atomicAdd(counter, 1) == B - 1) ? 1 : 0;
    __syncthreads();
    if (s_last) {
        __threadfence();
        // loc total (fixed-order: thread-strided + wave + cross-wave)
        float la = 0.0f;
        for (int i = tid; i < nblk; i += 1024) la += loc_part[i];
        la = waveSumF(la);
        if (lane == 0) s_f[wid] = la;
        __syncthreads();
        if (tid < 64) {
            int npT = 0; float cp = 0.0f, chd = 0.0f;
            for (int bb = tid; bb < B; bb += 64) {
                npT += n_pos[bb]; cp += ce_pos[bb]; chd += ce_hard[bb];
            }
            #pragma unroll
            for (int off = 32; off; off >>= 1) {
                npT += __shfl_xor(npT, off);
                cp  += __shfl_xor(cp, off);
                chd += __shfl_xor(chd, off);
            }
            if (tid == 0) {
                float latot = 0.0f;
                #pragma unroll
                for (int w = 0; w < 16; ++w) latot += s_f[w];
                float npt = (float)npT;
                out[0] = (chd + cp) / npt + latot / (npt * 4.0f);
            }
        }
    }
}

extern "C" void kernel_launch(void* const* d_in, const int* in_sizes, int n_in,
                              void* d_out, int out_size, void* d_ws, size_t ws_size,
                              hipStream_t stream) {
    const float* predict_locs  = (const float*)d_in[0];
    const float* predict_confs = (const float*)d_in[1];
    const float* target_boxes  = (const float*)d_in[2];
    const int*   target_labels = (const int*)d_in[3];
    const float* priors        = (const float*)d_in[4];

    const int P = in_sizes[4] / 4;             // 8732
    const int B = in_sizes[0] / (P * 4);       // 64
    const int rows = B * P;                    // 558848
    const int nmatch = B * CH;                 // 256
    const int nblk = rows / 256;               // 2183

    char* ws = (char*)d_ws;
    unsigned long long* okey_part = (unsigned long long*)ws;
    ws += (size_t)nmatch * O_C * sizeof(unsigned long long);
    float* ce      = (float*)ws; ws += (size_t)rows * sizeof(float);
    float* loc_p   = (float*)ws; ws += (size_t)nblk * sizeof(float);
    int*   n_pos   = (int*)ws;   ws += (size_t)B * sizeof(int);
    float* ce_pos  = (float*)ws; ws += (size_t)B * sizeof(float);
    float* ce_hard = (float*)ws; ws += (size_t)B * sizeof(float);
    int*   counter = (int*)ws;   ws += sizeof(int);

    match_okey<<<nmatch, 256, 0, stream>>>(target_boxes, priors, okey_part,
                                           counter, P);
    ce_stream<<<nblk, 256, 0, stream>>>(predict_confs, okey_part,
                                        target_boxes, target_labels, priors,
                                        predict_locs, ce, loc_p, P, rows);
    hard_finalize<<<B, 1024, 0, stream>>>(ce, loc_p, n_pos, ce_pos, ce_hard,
                                          counter, (float*)d_out, P, B, nblk);
}

// Round 16
// 94.250 us; speedup vs baseline: 1.5499x; 1.0630x over previous
//
#include <hip/hip_runtime.h>
#include <cstdint>
#include <cstddef>

constexpr int O_C   = 16;     // objects per image
constexpr int P_MAX = 8732;   // priors
constexpr int CH    = 4;      // match chunks per batch
constexpr int CHP   = 2183;   // priors per chunk (4*2183 = 8732)

__device__ __forceinline__ float waveSumF(float v) {
    #pragma unroll
    for (int off = 32; off; off >>= 1) v += __shfl_xor(v, off);
    return v;
}
__device__ __forceinline__ int waveSumI(int v) {
    #pragma unroll
    for (int off = 32; off; off >>= 1) v += __shfl_xor(v, off);
    return v;
}

// ---------------------------------------------------------------------------
// A1: per-prior IoU argmax over objects + per-(chunk,object) best-prior key.
// grid = B*CH blocks, 256 thr. Also resets the K2 completion counter.
// ---------------------------------------------------------------------------
__global__ __launch_bounds__(256) void matchA1(
    const float* __restrict__ target_boxes,   // [B,O,4] xyxy
    const float* __restrict__ priors,         // [P,4] cxcywh
    float* __restrict__ ov_out,               // [B,P]
    unsigned char* __restrict__ obj_out,      // [B,P]
    unsigned long long* __restrict__ okey_part, // [B*CH*O]
    int* __restrict__ counter,
    int P)
{
    const int b    = blockIdx.x / CH;
    const int c    = blockIdx.x % CH;
    const int tid  = threadIdx.x;
    const int lane = tid & 63;
    const int wid  = tid >> 6;

    if (blockIdx.x == 0 && tid == 0) *counter = 0;

    __shared__ float bx0[O_C], by0[O_C], bx1[O_C], by1[O_C], barea[O_C];
    __shared__ unsigned long long s_wb[O_C * 4];

    if (tid < O_C) {
        const float* tb = target_boxes + ((size_t)b * O_C + tid) * 4;
        float x0 = tb[0], y0 = tb[1], x1 = tb[2], y1 = tb[3];
        bx0[tid] = x0; by0[tid] = y0; bx1[tid] = x1; by1[tid] = y1;
        barea[tid] = (x1 - x0) * (y1 - y0);
    }
    __syncthreads();

    float bi[O_C]; int bp[O_C];
    #pragma unroll
    for (int o = 0; o < O_C; ++o) { bi[o] = -1.0f; bp[o] = 0; }

    const int p0 = c * CHP, p1 = min(p0 + CHP, P);
    for (int p = p0 + tid; p < p1; p += 256) {
        float4 pr = reinterpret_cast<const float4*>(priors)[p];
        float px0 = pr.x - pr.z * 0.5f, py0 = pr.y - pr.w * 0.5f;
        float px1 = pr.x + pr.z * 0.5f, py1 = pr.y + pr.w * 0.5f;
        float parea = (px1 - px0) * (py1 - py0);
        float bv = -1.0f; int bo = 0;
        #pragma unroll
        for (int o = 0; o < O_C; ++o) {
            float ix0 = fmaxf(px0, bx0[o]), iy0 = fmaxf(py0, by0[o]);
            float ix1 = fminf(px1, bx1[o]), iy1 = fminf(py1, by1[o]);
            float iw = fmaxf(ix1 - ix0, 0.0f), ih = fmaxf(iy1 - iy0, 0.0f);
            float inter = iw * ih;
            float iou = inter / (barea[o] + parea - inter);
            if (iou > bv) { bv = iou; bo = o; }          // first-max (argmax over o)
            if (iou > bi[o]) { bi[o] = iou; bp[o] = p; } // strict > -> smallest p
        }
        ov_out[(size_t)b * P + p]  = bv;
        obj_out[(size_t)b * P + p] = (unsigned char)bo;
    }

    // reduce per-object candidates: key = iou_bits<<32 | ~p (ties -> smaller p)
    #pragma unroll
    for (int o = 0; o < O_C; ++o) {
        unsigned long long k = (bi[o] >= 0.0f)
            ? (((unsigned long long)__float_as_uint(bi[o]) << 32) |
               (unsigned long long)(0xFFFFFFFFu - (unsigned)bp[o]))
            : 0ull;
        #pragma unroll
        for (int off = 32; off; off >>= 1) {
            unsigned long long k2 = __shfl_xor(k, off);
            if (k2 > k) k = k2;
        }
        if (lane == 0) s_wb[o * 4 + wid] = k;
    }
    __syncthreads();
    if (tid < O_C) {
        unsigned long long k = s_wb[tid * 4];
        #pragma unroll
        for (int w = 1; w < 4; ++w) if (s_wb[tid * 4 + w] > k) k = s_wb[tid * 4 + w];
        okey_part[(size_t)blockIdx.x * O_C + tid] = k;   // [b][c][o]
    }
}

// ---------------------------------------------------------------------------
// B-stream: thread-per-row fused CE (champion). 21 aligned dwordx4 loads per
// row via the 16B-aligned window covering floats [81r, 81r+81); head/tail
// masked with -3e38. Online LSE, two alternating chains. Label + loc fused;
// SIGNED ce output.
// ---------------------------------------------------------------------------
__global__ __launch_bounds__(256) void ce_stream(
    const float* __restrict__ confs,            // [rows,81]
    const float* __restrict__ ov_in,            // [rows]
    const unsigned char* __restrict__ obj_in,   // [rows]
    const unsigned long long* __restrict__ okey_part, // [B*CH*O]
    const float* __restrict__ target_boxes,     // [B,O,4]
    const int*   __restrict__ target_labels,    // [B,O]
    const float* __restrict__ priors,           // [P,4]
    const float* __restrict__ predict_locs,     // [rows,4]
    float* __restrict__ ce_out,                 // [rows] signed
    float* __restrict__ loc_part,               // [nblocks]
    int P, int rows)
{
    const int tid  = threadIdx.x;
    const int lane = tid & 63;
    const int wid  = tid >> 6;
    const int row0 = blockIdx.x * 256;
    const int row  = row0 + tid;

    __shared__ float4 tbox[2][O_C];
    __shared__ int    tlab[2][O_C], topr[2][O_C];
    __shared__ float  s_facc[4];

    const int b0     = row0 / P;
    const int rsplit = min(row0 + 256, (b0 + 1) * P);
    const int b1     = (rsplit < row0 + 256) ? b0 + 1 : b0;

    if (tid < 2 * O_C) {
        const int seg = tid >> 4, o = tid & 15;
        const int bb  = seg ? b1 : b0;
        const float* tb = target_boxes + ((size_t)bb * O_C + o) * 4;
        tbox[seg][o] = make_float4(tb[0], tb[1], tb[2], tb[3]);
        tlab[seg][o] = target_labels[(size_t)bb * O_C + o];
        unsigned long long kk = 0ull;
        #pragma unroll
        for (int cc = 0; cc < CH; ++cc) {
            unsigned long long k2 = okey_part[((size_t)bb * CH + cc) * O_C + o];
            if (k2 > kk) kk = k2;
        }
        topr[seg][o] = (int)(0xFFFFFFFFu - (unsigned)(kk & 0xFFFFFFFFull));
    }
    __syncthreads();

    // ---- streaming LSE over aligned dwordx4 window ----
    const int phase = row & 3;                 // (81*row) % 4 == row % 4
    const float4* vp = reinterpret_cast<const float4*>(confs)
                     + (((size_t)row * 81) >> 2);

    float mA = -3.0e38f, sA = 0.0f;
    float mB = -3.0e38f, sB = 0.0f;
    #pragma unroll
    for (int j = 0; j < 21; ++j) {
        float4 v = vp[j];
        const int eb = 4 * j - phase;
        float x0 = ((unsigned)(eb + 0) < 81u) ? v.x : -3.0e38f;
        float x1 = ((unsigned)(eb + 1) < 81u) ? v.y : -3.0e38f;
        float x2 = ((unsigned)(eb + 2) < 81u) ? v.z : -3.0e38f;
        float x3 = ((unsigned)(eb + 3) < 81u) ? v.w : -3.0e38f;
        float m4 = fmaxf(fmaxf(x0, x1), fmaxf(x2, x3));
        if (j & 1) {
            float mn = fmaxf(mB, m4);
            sB = sB * __expf(mB - mn)
               + __expf(x0 - mn) + __expf(x1 - mn)
               + __expf(x2 - mn) + __expf(x3 - mn);
            mB = mn;
        } else {
            float mn = fmaxf(mA, m4);
            sA = sA * __expf(mA - mn)
               + __expf(x0 - mn) + __expf(x1 - mn)
               + __expf(x2 - mn) + __expf(x3 - mn);
            mA = mn;
        }
    }
    float m = fmaxf(mA, mB);
    float s = sA * __expf(mA - m) + sB * __expf(mB - m);

    // ---- label + signed ce + loc partial ----
    const int seg = (row >= rsplit) ? 1 : 0;
    const int bb  = seg ? b1 : b0;
    const int p   = row - bb * P;
    float ovv = ov_in[row];
    int   obj = obj_in[row];
    #pragma unroll
    for (int o = 0; o < O_C; ++o)              // ascending -> last write wins
        if (topr[seg][o] == p) { obj = o; ovv = 1.0f; }
    const int l = (ovv < 0.5f) ? 0 : tlab[seg][obj];

    float xl  = confs[(size_t)row * 81 + l];   // L1-hot after the stream
    float cev = m + __logf(s) - xl;
    ce_out[row] = l ? -cev : cev;              // sign bit carries pos/neg

    float locacc = 0.0f;
    if (l) {
        float4 pr = reinterpret_cast<const float4*>(priors)[p];
        float4 tb = tbox[seg][obj];
        float cx = (tb.x + tb.z) * 0.5f, cy = (tb.y + tb.w) * 0.5f;
        float w  = tb.z - tb.x,          h  = tb.w - tb.y;
        float g0 = (cx - pr.x) / (pr.z * 0.1f);
        float g1 = (cy - pr.y) / (pr.w * 0.1f);
        float g2 = logf(w / pr.z) / 0.2f;
        float g3 = logf(h / pr.w) / 0.2f;
        float4 pl = reinterpret_cast<const float4*>(predict_locs)[row];
        locacc = fabsf(pl.x - g0) + fabsf(pl.y - g1) +
                 fabsf(pl.z - g2) + fabsf(pl.w - g3);
    }
    float a = waveSumF(locacc);
    if (lane == 0) s_facc[wid] = a;
    __syncthreads();
    if (tid == 0)
        loc_part[blockIdx.x] = s_facc[0] + s_facc[1] + s_facc[2] + s_facc[3];
}

// ---------------------------------------------------------------------------
// C: per-batch hard-negative mining from signed ce + LAST-BLOCK finalize.
// ---------------------------------------------------------------------------
__global__ __launch_bounds__(1024) void hard_finalize(
    const float* __restrict__ ce,       // [B,P] signed
    const float* __restrict__ loc_part, // [nblk]
    int*   __restrict__ n_pos,          // [B]
    float* __restrict__ ce_pos,         // [B]
    float* __restrict__ ce_hard,        // [B]
    int*   __restrict__ counter,
    float* __restrict__ out,
    int P, int B, int nblk)
{
    const int b    = blockIdx.x;
    const int tid  = threadIdx.x;
    const int lane = tid & 63;
    const int wid  = tid >> 6;

    __shared__ float s_v[P_MAX];
    __shared__ unsigned int hist[16][256];
    __shared__ unsigned int s_sel;
    __shared__ int s_kr, s_last;
    __shared__ float s_f[16], s_f2[16];
    __shared__ int s_i[16];

    const size_t base = (size_t)b * P;
    float possum = 0.0f, negsum = 0.0f;
    int cnt = 0;
    for (int p = tid; p < P; p += 1024) {
        float c = ce[base + p];
        unsigned u = __float_as_uint(c);
        float sv;
        if (u >> 31) { possum += -c; ++cnt; sv = 0.0f; }
        else         { negsum += c;         sv = c;    }
        s_v[p] = sv;
    }
    possum = waveSumF(possum);
    negsum = waveSumF(negsum);
    cnt    = waveSumI(cnt);
    if (lane == 0) { s_f[wid] = possum; s_f2[wid] = negsum; s_i[wid] = cnt; }
    __syncthreads();
    float negsum_t = 0.0f, possum_t = 0.0f; int np = 0;
    #pragma unroll
    for (int w = 0; w < 16; ++w) { negsum_t += s_f2[w]; possum_t += s_f[w]; np += s_i[w]; }
    if (tid == 0) { ce_pos[b] = possum_t; n_pos[b] = np; }

    const int K = 3 * np;
    if (K <= 0) {
        if (tid == 0) ce_hard[b] = 0.0f;
    } else if (K >= P) {
        if (tid == 0) ce_hard[b] = negsum_t;
    } else {
        unsigned int prefix = 0; int kr = K;
        for (int shift = 24; shift >= 0; shift -= 8) {
            for (int i = tid; i < 16 * 256; i += 1024) (&hist[0][0])[i] = 0;
            __syncthreads();
            unsigned int maskHi = (shift == 24) ? 0u : (0xFFFFFFFFu << (shift + 8));
            for (int p = tid; p < P; p += 1024) {
                unsigned int u = __float_as_uint(s_v[p]);
                if ((u & maskHi) == prefix) atomicAdd(&hist[wid][(u >> shift) & 255], 1u);
            }
            __syncthreads();
            if (wid == 0) {
                unsigned h0 = 0, h1 = 0, h2 = 0, h3 = 0;
                #pragma unroll 4
                for (int w = 0; w < 16; ++w) {
                    h0 += hist[w][lane * 4 + 0];
                    h1 += hist[w][lane * 4 + 1];
                    h2 += hist[w][lane * 4 + 2];
                    h3 += hist[w][lane * 4 + 3];
                }
                unsigned own = h0 + h1 + h2 + h3;
                unsigned t = own;                    // inclusive suffix over lanes
                #pragma unroll
                for (int off = 1; off < 64; off <<= 1) {
                    unsigned u = __shfl_down(t, off);
                    if (lane + off >= 64) u = 0;
                    t += u;
                }
                unsigned Tnext = t - own;            // strictly-higher lanes
                unsigned cum3 = Tnext;
                unsigned cum2 = cum3 + h3;
                unsigned cum1 = cum2 + h2;
                unsigned cum0 = cum1 + h1;
                unsigned kru = (unsigned)kr;
                int selj = -1; unsigned cg = 0;
                if      (cum3 < kru && kru <= cum3 + h3) { selj = 3; cg = cum3; }
                else if (cum2 < kru && kru <= cum2 + h2) { selj = 2; cg = cum2; }
                else if (cum1 < kru && kru <= cum1 + h1) { selj = 1; cg = cum1; }
                else if (cum0 < kru && kru <= cum0 + h0) { selj = 0; cg = cum0; }
                if (selj >= 0) {
                    s_sel = prefix | ((unsigned)(lane * 4 + selj) << shift);
                    s_kr  = kr - (int)cg;
                }
            }
            __syncthreads();
            prefix = s_sel; kr = s_kr;
            __syncthreads();
        }

        float sumgt = 0.0f;
        for (int p = tid; p < P; p += 1024) {
            unsigned int u = __float_as_uint(s_v[p]);
            if (u > prefix) sumgt += s_v[p];
        }
        sumgt = waveSumF(sumgt);
        if (lane == 0) s_f[wid] = sumgt;
        __syncthreads();
        if (tid == 0) {
            float sg = 0.0f;
            #pragma unroll
            for (int w = 0; w < 16; ++w) sg += s_f[w];
            ce_hard[b] = sg + (float)kr * __uint_as_float(prefix);
        }
    }

    // ---- last-block finalize (all per-batch outputs written first) ----
    __threadfence();
    __syncthreads();
    if (tid == 0) s_last = (atomicAdd(counter, 1) == B - 1) ? 1 : 0;
    __syncthreads();
    if (s_last) {
        __threadfence();
        float la = 0.0f;
        for (int i = tid; i < nblk; i += 1024) la += loc_part[i];
        la = waveSumF(la);
        if (lane == 0) s_f[wid] = la;
        __syncthreads();
        if (tid < 64) {
            int npT = 0; float cp = 0.0f, chd = 0.0f;
            for (int bb = tid; bb < B; bb += 64) {
                npT += n_pos[bb]; cp += ce_pos[bb]; chd += ce_hard[bb];
            }
            #pragma unroll
            for (int off = 32; off; off >>= 1) {
                npT += __shfl_xor(npT, off);
                cp  += __shfl_xor(cp, off);
                chd += __shfl_xor(chd, off);
            }
            if (tid == 0) {
                float latot = 0.0f;
                #pragma unroll
                for (int w = 0; w < 16; ++w) latot += s_f[w];
                float npt = (float)npT;
                out[0] = (chd + cp) / npt + latot / (npt * 4.0f);
            }
        }
    }
}

extern "C" void kernel_launch(void* const* d_in, const int* in_sizes, int n_in,
                              void* d_out, int out_size, void* d_ws, size_t ws_size,
                              hipStream_t stream) {
    const float* predict_locs  = (const float*)d_in[0];
    const float* predict_confs = (const float*)d_in[1];
    const float* target_boxes  = (const float*)d_in[2];
    const int*   target_labels = (const int*)d_in[3];
    const float* priors        = (const float*)d_in[4];

    const int P = in_sizes[4] / 4;             // 8732
    const int B = in_sizes[0] / (P * 4);       // 64
    const int rows = B * P;                    // 558848
    const int nblk = rows / 256;               // 2183 (rows % 256 == 0)

    char* ws = (char*)d_ws;
    unsigned long long* okey_part = (unsigned long long*)ws;
    ws += (size_t)B * CH * O_C * sizeof(unsigned long long);
    float* ce      = (float*)ws; ws += (size_t)rows * sizeof(float);
    float* ov      = (float*)ws; ws += (size_t)rows * sizeof(float);
    float* loc_p   = (float*)ws; ws += (size_t)nblk * sizeof(float);
    int*   n_pos   = (int*)ws;   ws += (size_t)B * sizeof(int);
    float* ce_pos  = (float*)ws; ws += (size_t)B * sizeof(float);
    float* ce_hard = (float*)ws; ws += (size_t)B * sizeof(float);
    int*   counter = (int*)ws;   ws += sizeof(int);
    unsigned char* obj = (unsigned char*)ws; ws += (size_t)rows;

    matchA1<<<B * CH, 256, 0, stream>>>(target_boxes, priors, ov, obj,
                                        okey_part, counter, P);
    ce_stream<<<nblk, 256, 0, stream>>>(predict_confs, ov, obj, okey_part,
                                        target_boxes, target_labels, priors,
                                        predict_locs, ce, loc_p, P, rows);
    hard_finalize<<<B, 1024, 0, stream>>>(ce, loc_p, n_pos, ce_pos, ce_hard,
                                          counter, (float*)d_out, P, B, nblk);
}

// Round 17
// 77.835 us; speedup vs baseline: 1.8768x; 1.2109x over previous
//
#include <hip/hip_runtime.h>
#include <cstdint>
#include <cstddef>

constexpr int O_C   = 16;     // objects per image
constexpr int P_MAX = 8732;   // priors
constexpr int CH    = 4;      // match chunks per batch
constexpr int CHP   = 2183;   // priors per chunk (4*2183 = 8732)

__device__ __forceinline__ float waveSumF(float v) {
    #pragma unroll
    for (int off = 32; off; off >>= 1) v += __shfl_xor(v, off);
    return v;
}
__device__ __forceinline__ int waveSumI(int v) {
    #pragma unroll
    for (int off = 32; off; off >>= 1) v += __shfl_xor(v, off);
    return v;
}

// ---------------------------------------------------------------------------
// A1: per-prior IoU argmax over objects + per-(chunk,object) best-prior key.
// grid = B*CH blocks, 256 thr. No atomics: each block owns okey_part slice.
// ---------------------------------------------------------------------------
__global__ __launch_bounds__(256) void matchA1(
    const float* __restrict__ target_boxes,   // [B,O,4] xyxy
    const float* __restrict__ priors,         // [P,4] cxcywh
    float* __restrict__ ov_out,               // [B,P]
    unsigned char* __restrict__ obj_out,      // [B,P]
    unsigned long long* __restrict__ okey_part, // [B*CH*O]
    int P)
{
    const int b    = blockIdx.x / CH;
    const int c    = blockIdx.x % CH;
    const int tid  = threadIdx.x;
    const int lane = tid & 63;
    const int wid  = tid >> 6;

    __shared__ float bx0[O_C], by0[O_C], bx1[O_C], by1[O_C], barea[O_C];
    __shared__ unsigned long long s_wb[O_C * 4];

    if (tid < O_C) {
        const float* tb = target_boxes + ((size_t)b * O_C + tid) * 4;
        float x0 = tb[0], y0 = tb[1], x1 = tb[2], y1 = tb[3];
        bx0[tid] = x0; by0[tid] = y0; bx1[tid] = x1; by1[tid] = y1;
        barea[tid] = (x1 - x0) * (y1 - y0);
    }
    __syncthreads();

    float bi[O_C]; int bp[O_C];
    #pragma unroll
    for (int o = 0; o < O_C; ++o) { bi[o] = -1.0f; bp[o] = 0; }

    const int p0 = c * CHP, p1 = min(p0 + CHP, P);
    for (int p = p0 + tid; p < p1; p += 256) {
        float4 pr = reinterpret_cast<const float4*>(priors)[p];
        float px0 = pr.x - pr.z * 0.5f, py0 = pr.y - pr.w * 0.5f;
        float px1 = pr.x + pr.z * 0.5f, py1 = pr.y + pr.w * 0.5f;
        float parea = (px1 - px0) * (py1 - py0);
        float bv = -1.0f; int bo = 0;
        #pragma unroll
        for (int o = 0; o < O_C; ++o) {
            float ix0 = fmaxf(px0, bx0[o]), iy0 = fmaxf(py0, by0[o]);
            float ix1 = fminf(px1, bx1[o]), iy1 = fminf(py1, by1[o]);
            float iw = fmaxf(ix1 - ix0, 0.0f), ih = fmaxf(iy1 - iy0, 0.0f);
            float inter = iw * ih;
            float iou = inter / (barea[o] + parea - inter);
            if (iou > bv) { bv = iou; bo = o; }          // first-max (argmax over o)
            if (iou > bi[o]) { bi[o] = iou; bp[o] = p; } // strict > -> smallest p
        }
        ov_out[(size_t)b * P + p]  = bv;
        obj_out[(size_t)b * P + p] = (unsigned char)bo;
    }

    // reduce per-object candidates: key = iou_bits<<32 | ~p (ties -> smaller p)
    #pragma unroll
    for (int o = 0; o < O_C; ++o) {
        unsigned long long k = (bi[o] >= 0.0f)
            ? (((unsigned long long)__float_as_uint(bi[o]) << 32) |
               (unsigned long long)(0xFFFFFFFFu - (unsigned)bp[o]))
            : 0ull;
        #pragma unroll
        for (int off = 32; off; off >>= 1) {
            unsigned long long k2 = __shfl_xor(k, off);
            if (k2 > k) k = k2;
        }
        if (lane == 0) s_wb[o * 4 + wid] = k;
    }
    __syncthreads();
    if (tid < O_C) {
        unsigned long long k = s_wb[tid * 4];
        #pragma unroll
        for (int w = 1; w < 4; ++w) if (s_wb[tid * 4 + w] > k) k = s_wb[tid * 4 + w];
        okey_part[(size_t)blockIdx.x * O_C + tid] = k;   // [b][c][o]
    }
}

// ---------------------------------------------------------------------------
// B-stream: thread-per-row fused CE. 21 ALIGNED float4 (dwordx4) loads per
// row via the 16B-aligned window covering floats [81r, 81r+81); head/tail
// elements masked with -3e38 (predicated, no divergence). Online LSE with
// two alternating chains. Label + loc partial fused; SIGNED ce output.
// ---------------------------------------------------------------------------
__global__ __launch_bounds__(256) void ce_stream(
    const float* __restrict__ confs,            // [rows,81]
    const float* __restrict__ ov_in,            // [rows]
    const unsigned char* __restrict__ obj_in,   // [rows]
    const unsigned long long* __restrict__ okey_part, // [B*CH*O]
    const float* __restrict__ target_boxes,     // [B,O,4]
    const int*   __restrict__ target_labels,    // [B,O]
    const float* __restrict__ priors,           // [P,4]
    const float* __restrict__ predict_locs,     // [rows,4]
    float* __restrict__ ce_out,                 // [rows] signed
    float* __restrict__ loc_part,               // [nblocks]
    int P, int rows)
{
    const int tid  = threadIdx.x;
    const int lane = tid & 63;
    const int wid  = tid >> 6;
    const int row0 = blockIdx.x * 256;
    const int row  = row0 + tid;

    __shared__ float4 tbox[2][O_C];
    __shared__ int    tlab[2][O_C], topr[2][O_C];
    __shared__ float  s_facc[4];

    const int b0     = row0 / P;
    const int rsplit = min(row0 + 256, (b0 + 1) * P);
    const int b1     = (rsplit < row0 + 256) ? b0 + 1 : b0;

    if (tid < 2 * O_C) {
        const int seg = tid >> 4, o = tid & 15;
        const int bb  = seg ? b1 : b0;
        const float* tb = target_boxes + ((size_t)bb * O_C + o) * 4;
        tbox[seg][o] = make_float4(tb[0], tb[1], tb[2], tb[3]);
        tlab[seg][o] = target_labels[(size_t)bb * O_C + o];
        unsigned long long kk = 0ull;
        #pragma unroll
        for (int cc = 0; cc < CH; ++cc) {
            unsigned long long k2 = okey_part[((size_t)bb * CH + cc) * O_C + o];
            if (k2 > kk) kk = k2;
        }
        topr[seg][o] = (int)(0xFFFFFFFFu - (unsigned)(kk & 0xFFFFFFFFull));
    }
    __syncthreads();

    // ---- streaming LSE over aligned dwordx4 window ----
    // floats [81*row, 81*row+81) live in aligned float4s [(81r)>>2, (81r)>>2+21)
    // phase = (81*row) % 4 == row % 4; element e = 4j + i - phase, valid iff e in [0,81)
    const int phase = row & 3;
    const float4* vp = reinterpret_cast<const float4*>(confs) + (((size_t)row * 81) >> 2);

    float mA = -3.0e38f, sA = 0.0f;
    float mB = -3.0e38f, sB = 0.0f;
    #pragma unroll
    for (int j = 0; j < 21; ++j) {
        float4 v = vp[j];
        const int eb = 4 * j - phase;
        float x0 = ((unsigned)(eb + 0) < 81u) ? v.x : -3.0e38f;
        float x1 = ((unsigned)(eb + 1) < 81u) ? v.y : -3.0e38f;
        float x2 = ((unsigned)(eb + 2) < 81u) ? v.z : -3.0e38f;
        float x3 = ((unsigned)(eb + 3) < 81u) ? v.w : -3.0e38f;
        float m4 = fmaxf(fmaxf(x0, x1), fmaxf(x2, x3));
        if (j & 1) {
            float mn = fmaxf(mB, m4);
            sB = sB * __expf(mB - mn)
               + __expf(x0 - mn) + __expf(x1 - mn)
               + __expf(x2 - mn) + __expf(x3 - mn);
            mB = mn;
        } else {
            float mn = fmaxf(mA, m4);
            sA = sA * __expf(mA - mn)
               + __expf(x0 - mn) + __expf(x1 - mn)
               + __expf(x2 - mn) + __expf(x3 - mn);
            mA = mn;
        }
    }
    float m = fmaxf(mA, mB);
    float s = sA * __expf(mA - m) + sB * __expf(mB - m);

    // ---- label + signed ce + loc partial ----
    const int seg = (row >= rsplit) ? 1 : 0;
    const int bb  = seg ? b1 : b0;
    const int p   = row - bb * P;
    float ovv = ov_in[row];
    int   obj = obj_in[row];
    #pragma unroll
    for (int o = 0; o < O_C; ++o)              // ascending -> last write wins
        if (topr[seg][o] == p) { obj = o; ovv = 1.0f; }
    const int l = (ovv < 0.5f) ? 0 : tlab[seg][obj];

    float xl  = confs[(size_t)row * 81 + l];   // L1-hot after the stream
    float cev = m + __logf(s) - xl;
    ce_out[row] = l ? -cev : cev;              // sign bit carries pos/neg

    float locacc = 0.0f;
    if (l) {
        float4 pr = reinterpret_cast<const float4*>(priors)[p];
        float4 tb = tbox[seg][obj];
        float cx = (tb.x + tb.z) * 0.5f, cy = (tb.y + tb.w) * 0.5f;
        float w  = tb.z - tb.x,          h  = tb.w - tb.y;
        float g0 = (cx - pr.x) / (pr.z * 0.1f);
        float g1 = (cy - pr.y) / (pr.w * 0.1f);
        float g2 = logf(w / pr.z) / 0.2f;
        float g3 = logf(h / pr.w) / 0.2f;
        float4 pl = reinterpret_cast<const float4*>(predict_locs)[row];
        locacc = fabsf(pl.x - g0) + fabsf(pl.y - g1) +
                 fabsf(pl.z - g2) + fabsf(pl.w - g3);
    }
    float a = waveSumF(locacc);
    if (lane == 0) s_facc[wid] = a;
    __syncthreads();
    if (tid == 0)
        loc_part[blockIdx.x] = s_facc[0] + s_facc[1] + s_facc[2] + s_facc[3];
}

// ---------------------------------------------------------------------------
// C: per-batch hard-negative mining from signed ce. Derives n_pos via
// signbit count; exact top-K sum via radix select (privatized histograms +
// wave-parallel suffix-scan digit select).
// ---------------------------------------------------------------------------
__global__ __launch_bounds__(1024) void hard_kernel(
    const float* __restrict__ ce,      // [B,P] signed
    int*   __restrict__ n_pos,         // [B]
    float* __restrict__ ce_pos,        // [B]
    float* __restrict__ ce_hard,       // [B]
    int P)
{
    const int b    = blockIdx.x;
    const int tid  = threadIdx.x;
    const int lane = tid & 63;
    const int wid  = tid >> 6;

    __shared__ float s_v[P_MAX];
    __shared__ unsigned int hist[16][256];
    __shared__ unsigned int s_sel;
    __shared__ int s_kr;
    __shared__ float s_f[16], s_f2[16];
    __shared__ int s_i[16];

    const size_t base = (size_t)b * P;
    float possum = 0.0f, negsum = 0.0f;
    int cnt = 0;
    for (int p = tid; p < P; p += 1024) {
        float c = ce[base + p];
        unsigned u = __float_as_uint(c);
        float sv;
        if (u >> 31) { possum += -c; ++cnt; sv = 0.0f; }
        else         { negsum += c;         sv = c;    }
        s_v[p] = sv;
    }
    possum = waveSumF(possum);
    negsum = waveSumF(negsum);
    cnt    = waveSumI(cnt);
    if (lane == 0) { s_f[wid] = possum; s_f2[wid] = negsum; s_i[wid] = cnt; }
    __syncthreads();
    float negsum_t = 0.0f, possum_t = 0.0f; int np = 0;
    #pragma unroll
    for (int w = 0; w < 16; ++w) { negsum_t += s_f2[w]; possum_t += s_f[w]; np += s_i[w]; }
    if (tid == 0) { ce_pos[b] = possum_t; n_pos[b] = np; }

    const int K = 3 * np;
    if (K <= 0) { if (tid == 0) ce_hard[b] = 0.0f; return; }
    if (K >= P) { if (tid == 0) ce_hard[b] = negsum_t; return; }

    unsigned int prefix = 0; int kr = K;
    for (int shift = 24; shift >= 0; shift -= 8) {
        for (int i = tid; i < 16 * 256; i += 1024) (&hist[0][0])[i] = 0;
        __syncthreads();
        unsigned int maskHi = (shift == 24) ? 0u : (0xFFFFFFFFu << (shift + 8));
        for (int p = tid; p < P; p += 1024) {
            unsigned int u = __float_as_uint(s_v[p]);
            if ((u & maskHi) == prefix) atomicAdd(&hist[wid][(u >> shift) & 255], 1u);
        }
        __syncthreads();
        if (wid == 0) {
            unsigned h0 = 0, h1 = 0, h2 = 0, h3 = 0;
            #pragma unroll 4
            for (int w = 0; w < 16; ++w) {
                h0 += hist[w][lane * 4 + 0];
                h1 += hist[w][lane * 4 + 1];
                h2 += hist[w][lane * 4 + 2];
                h3 += hist[w][lane * 4 + 3];
            }
            unsigned own = h0 + h1 + h2 + h3;
            unsigned t = own;                    // inclusive suffix over lanes
            #pragma unroll
            for (int off = 1; off < 64; off <<= 1) {
                unsigned u = __shfl_down(t, off);
                if (lane + off >= 64) u = 0;
                t += u;
            }
            unsigned Tnext = t - own;            // strictly-higher lanes
            unsigned cum3 = Tnext;
            unsigned cum2 = cum3 + h3;
            unsigned cum1 = cum2 + h2;
            unsigned cum0 = cum1 + h1;
            unsigned kru = (unsigned)kr;
            int selj = -1; unsigned cg = 0;
            if      (cum3 < kru && kru <= cum3 + h3) { selj = 3; cg = cum3; }
            else if (cum2 < kru && kru <= cum2 + h2) { selj = 2; cg = cum2; }
            else if (cum1 < kru && kru <= cum1 + h1) { selj = 1; cg = cum1; }
            else if (cum0 < kru && kru <= cum0 + h0) { selj = 0; cg = cum0; }
            if (selj >= 0) {
                s_sel = prefix | ((unsigned)(lane * 4 + selj) << shift);
                s_kr  = kr - (int)cg;
            }
        }
        __syncthreads();
        prefix = s_sel; kr = s_kr;
        __syncthreads();
    }

    float sumgt = 0.0f;
    for (int p = tid; p < P; p += 1024) {
        unsigned int u = __float_as_uint(s_v[p]);
        if (u > prefix) sumgt += s_v[p];
    }
    sumgt = waveSumF(sumgt);
    if (lane == 0) s_f[wid] = sumgt;
    __syncthreads();
    if (tid == 0) {
        float sg = 0.0f;
        #pragma unroll
        for (int w = 0; w < 16; ++w) sg += s_f[w];
        ce_hard[b] = sg + (float)kr * __uint_as_float(prefix);
    }
}

// ---------------------------------------------------------------------------
// D: finalize scalar loss. 256 thr, deterministic fixed-order sums.
// ---------------------------------------------------------------------------
__global__ __launch_bounds__(256) void finalize_kernel(
    const int*   __restrict__ n_pos,    // [B]
    const float* __restrict__ ce_pos,   // [B]
    const float* __restrict__ ce_hard,  // [B]
    const float* __restrict__ loc_part, // [nblk]
    float* __restrict__ out, int B, int nblk)
{
    __shared__ float s_f[4];
    __shared__ float s_res[3];
    const int tid  = threadIdx.x;
    const int lane = tid & 63;
    const int wid  = tid >> 6;

    float la = 0.0f;
    for (int i = tid; i < nblk; i += 256) la += loc_part[i];
    la = waveSumF(la);
    if (lane == 0) s_f[wid] = la;

    if (tid < 64) {
        int np = 0; float cp = 0.0f, ch = 0.0f;
        for (int b = lane; b < B; b += 64) {
            np += n_pos[b]; cp += ce_pos[b]; ch += ce_hard[b];
        }
        #pragma unroll
        for (int off = 32; off; off >>= 1) {
            np += __shfl_xor(np, off);
            cp += __shfl_xor(cp, off);
            ch += __shfl_xor(ch, off);
        }
        if (lane == 0) {
            s_res[0] = (float)np; s_res[1] = cp; s_res[2] = ch;
        }
    }
    __syncthreads();
    if (tid == 0) {
        float latot = s_f[0] + s_f[1] + s_f[2] + s_f[3];
        float npt = s_res[0];
        out[0] = (s_res[2] + s_res[1]) / npt + latot / (npt * 4.0f);
    }
}

extern "C" void kernel_launch(void* const* d_in, const int* in_sizes, int n_in,
                              void* d_out, int out_size, void* d_ws, size_t ws_size,
                              hipStream_t stream) {
    const float* predict_locs  = (const float*)d_in[0];
    const float* predict_confs = (const float*)d_in[1];
    const float* target_boxes  = (const float*)d_in[2];
    const int*   target_labels = (const int*)d_in[3];
    const float* priors        = (const float*)d_in[4];

    const int P = in_sizes[4] / 4;             // 8732
    const int B = in_sizes[0] / (P * 4);       // 64
    const int rows = B * P;                    // 558848
    const int nblk = rows / 256;               // 2183 (rows % 256 == 0)

    char* ws = (char*)d_ws;
    unsigned long long* okey_part = (unsigned long long*)ws;
    ws += (size_t)B * CH * O_C * sizeof(unsigned long long);
    float* ce      = (float*)ws; ws += (size_t)rows * sizeof(float);
    float* ov      = (float*)ws; ws += (size_t)rows * sizeof(float);
    float* loc_p   = (float*)ws; ws += (size_t)nblk * sizeof(float);
    int*   n_pos   = (int*)ws;   ws += (size_t)B * sizeof(int);
    float* ce_pos  = (float*)ws; ws += (size_t)B * sizeof(float);
    float* ce_hard = (float*)ws; ws += (size_t)B * sizeof(float);
    unsigned char* obj = (unsigned char*)ws; ws += (size_t)rows;

    matchA1<<<B * CH, 256, 0, stream>>>(target_boxes, priors, ov, obj, okey_part, P);
    ce_stream<<<nblk, 256, 0, stream>>>(predict_confs, ov, obj, okey_part,
                                        target_boxes, target_labels, priors,
                                        predict_locs, ce, loc_p, P, rows);
    hard_kernel<<<B, 1024, 0, stream>>>(ce, n_pos, ce_pos, ce_hard, P);
    finalize_kernel<<<1, 256, 0, stream>>>(n_pos, ce_pos, ce_hard, loc_p,
                                           (float*)d_out, B, rows / 256);
}